// Round 8
// baseline (237.256 us; speedup 1.0000x reference)
//
#include <hip/hip_runtime.h>
#include <hip/hip_bf16.h>
#include <cstdint>
#include <cstddef>

typedef __bf16 bf16x8 __attribute__((ext_vector_type(8)));
typedef float f32x4 __attribute__((ext_vector_type(4)));
using u16 = unsigned short;

#define NUM_GROUPS_C 2048

__device__ __forceinline__ u16 f2bf(float f) {
  union { float f; uint32_t u; } c; c.f = f;
  uint32_t r = (c.u + 0x7fffu + ((c.u >> 16) & 1u)) >> 16;
  return (u16)r;
}
__device__ __forceinline__ float bf2f(u16 h) {
  union { uint32_t u; float f; } c; c.u = ((uint32_t)h) << 16; return c.f;
}

__device__ __forceinline__ void glds16(const u16* g, void* l) {
  __builtin_amdgcn_global_load_lds((const __attribute__((address_space(1))) void*)g,
                                   (__attribute__((address_space(3))) void*)l, 16, 0, 0);
}

// ---------------- cast 3 weight matrices fp32 -> bf16 (one launch) ----------------
__global__ void cast_w3(const float* __restrict__ w0, const float* __restrict__ w1,
                        const float* __restrict__ w2,
                        u16* __restrict__ o0, u16* __restrict__ o1, u16* __restrict__ o2,
                        int n4) {
  const float* src = (blockIdx.y == 0) ? w0 : (blockIdx.y == 1) ? w1 : w2;
  u16* dst = (blockIdx.y == 0) ? o0 : (blockIdx.y == 1) ? o1 : o2;
  int i = blockIdx.x * blockDim.x + threadIdx.x;
  int stride = gridDim.x * blockDim.x;
  for (; i < n4; i += stride) {
    float4 v = reinterpret_cast<const float4*>(src)[i];
    uint2 o;
    o.x = (uint32_t)f2bf(v.x) | ((uint32_t)f2bf(v.y) << 16);
    o.y = (uint32_t)f2bf(v.z) | ((uint32_t)f2bf(v.w) << 16);
    reinterpret_cast<uint2*>(dst)[i] = o;
  }
}

// ---------------- bucket edges by group ----------------
__global__ void zero_i32(int* p, int n) {
  int i = blockIdx.x * blockDim.x + threadIdx.x;
  if (i < n) p[i] = 0;
}
__global__ void count_k(const int* __restrict__ ix, int* __restrict__ cnt, int E) {
  int e = blockIdx.x * blockDim.x + threadIdx.x;
  if (e < E) atomicAdd(&cnt[ix[e]], 1);
}
__global__ void scan_k(const int* __restrict__ cnt, int* __restrict__ offs,
                       int* __restrict__ cursor, int G) {
  __shared__ int part[256];
  int t = threadIdx.x;
  int gpt = G / 256;
  int base = t * gpt;
  int loc[8];
  int s = 0;
  for (int j = 0; j < gpt; ++j) { loc[j] = cnt[base + j]; s += loc[j]; }
  part[t] = s;
  __syncthreads();
  for (int off = 1; off < 256; off <<= 1) {
    int v = (t >= off) ? part[t - off] : 0;
    __syncthreads();
    part[t] += v;
    __syncthreads();
  }
  int run = part[t] - s;
  for (int j = 0; j < gpt; ++j) {
    offs[base + j] = run;
    cursor[base + j] = run;
    run += loc[j];
  }
}
__global__ void scatter_k(const int* __restrict__ ix, int* __restrict__ cursor,
                          int* __restrict__ elist, int E) {
  int e = blockIdx.x * blockDim.x + threadIdx.x;
  if (e < E) {
    int g = ix[e];
    int pos = atomicAdd(&cursor[g], 1);
    elist[pos] = e;
  }
}

// ============ fused f/g GEMM: fp32 A cast in-staging, 256x256 tile, BK=64, 8 waves ============
// C[m,n] = sum_k A[m,k]*B[n,k] + bias[n]; A (M,K) fp32 rm, B (N,K) bf16 rm.
// grid: (M/256)*4 blocks; ns = {g n-tile0, g n-tile1, f n-tile0, f n-tile1} (XCD-swizzled so
// the 4 ns-slots of one mt are L2-adjacent -> A panel fetched ~once per XCD).
// LDS swizzle convention (both A and B): LDS(row r, 16B-slot s) = global slot s^(r&7).
//   B: global_load_lds writes linearly -> pre-swizzle the SOURCE column.
//   A: reg-staged (fp32->bf16 cvt in regs) -> apply swizzle on ds_write address.
__global__ __launch_bounds__(512, 2)
void gemm256_fg(const float* __restrict__ A,
                const u16* __restrict__ B0, const u16* __restrict__ B1,
                const float* __restrict__ bias0, const float* __restrict__ bias1,
                u16* __restrict__ C0, u16* __restrict__ C1,
                int K, int N) {
  __shared__ u16 lds[2 * 32768];   // [buf][A:16384 u16 | B:16384 u16]

  const int tid  = threadIdx.x;
  const int lane = tid & 63;
  const int wid  = tid >> 6;
  const int wm   = wid >> 2;   // 0..1
  const int wn   = wid & 3;    // 0..3
  const int fr   = lane & 15;
  const int fq   = lane >> 4;
  const int swr  = fr & 7;     // read-side swizzle key (row&7 == fr&7; rows stride 16)

  // bijective XCD swizzle; ns fastest within mt for A-panel L2 reuse
  const int nwg = gridDim.x;
  const int cpx = nwg >> 3;
  const int wg  = blockIdx.x;
  const int swz = (wg & 7) * cpx + (wg >> 3);
  const int mt = swz >> 2;
  const int ns = swz & 3;
  const u16* Bm     = (ns < 2) ? B0 : B1;
  const float* bias = (ns < 2) ? bias0 : bias1;
  u16* C            = (ns < 2) ? C0 : C1;
  const int n0 = (ns & 1) * 256;
  const int m0 = mt * 256;

  // A reg-staging: thread t -> row ar = t>>1, col-half ah = t&1 (32 fp32 = 8 x dwordx4)
  const int ar = tid >> 1;
  const int ah = tid & 1;
  const float* Asrc = A + (size_t)(m0 + ar) * K + ah * 32;

  // B gload_lds: chunk c = i*512+tid -> LDS row c>>3, slot tid&7; source col pre-swizzled
  const int r8   = tid >> 3;
  const int scol = ((tid & 7) ^ (r8 & 7)) << 3;
  const u16* Bb = Bm + (size_t)n0 * K + scol;

  f32x4 aregs[8];
  auto loadA = [&](int k0) {
    #pragma unroll
    for (int k = 0; k < 8; ++k)
      aregs[k] = *reinterpret_cast<const f32x4*>(Asrc + k0 + k * 4);
  };
  auto stageB = [&](int buf, int k0) {
    u16* bufB = lds + buf * 32768 + 16384;
    #pragma unroll
    for (int i = 0; i < 4; ++i)
      glds16(Bb + (size_t)(i * 64 + r8) * K + k0, (char*)bufB + i * 8192 + wid * 1024);
  };
  auto writeA = [&](int buf) {
    u16* bufA = lds + buf * 32768;
    #pragma unroll
    for (int k = 0; k < 4; ++k) {
      bf16x8 w;
      #pragma unroll
      for (int j = 0; j < 4; ++j) {
        w[j]     = (__bf16)aregs[2 * k][j];
        w[4 + j] = (__bf16)aregs[2 * k + 1][j];
      }
      const int slot = (ah * 4 + k) ^ (ar & 7);
      *reinterpret_cast<bf16x8*>(&bufA[(size_t)ar * 64 + slot * 8]) = w;
    }
  };

  f32x4 acc[8][4] = {};
  const int NT = K >> 6;

  loadA(0);        // 8 vmem outstanding (oldest)
  stageB(0, 0);    // +4 = 12

  for (int t = 0; t < NT; ++t) {
    const int c = t & 1;
    __builtin_amdgcn_s_barrier();                      // prior readers of both bufs done
    asm volatile("s_waitcnt vmcnt(4)" ::: "memory");   // A(t) regs landed (B(t)'s 4 may remain)
    writeA(c);                                         // ds_write -> bufA[c]
    if (t + 1 < NT) {
      loadA((t + 1) << 6);                             // 8 vmem
      stageB(c ^ 1, (t + 1) << 6);                     // 4 vmem
      asm volatile("s_waitcnt vmcnt(12) lgkmcnt(0)" ::: "memory");  // B(t) landed + my ds_writes done
    } else {
      asm volatile("s_waitcnt vmcnt(0) lgkmcnt(0)" ::: "memory");
    }
    __builtin_amdgcn_s_barrier();                      // all waves' buf c complete

    const char* sA_ = (const char*)(lds + c * 32768);
    const char* sB_ = sA_ + 32768;

    #pragma unroll
    for (int q = 0; q < 4; ++q) {                      // free-flow quadrants
      const int qm = q >> 1, qn = q & 1;
      bf16x8 av[4][2], bv[2][2];
      #pragma unroll
      for (int j = 0; j < 4; ++j)
        #pragma unroll
        for (int kk = 0; kk < 2; ++kk)
          av[j][kk] = *(const bf16x8*)(sA_ + ((wm * 128 + (qm * 4 + j) * 16 + fr) << 7)
                                           + ((((kk << 2) | fq) ^ swr) << 4));
      #pragma unroll
      for (int j = 0; j < 2; ++j)
        #pragma unroll
        for (int kk = 0; kk < 2; ++kk)
          bv[j][kk] = *(const bf16x8*)(sB_ + ((wn * 64 + (qn * 2 + j) * 16 + fr) << 7)
                                           + ((((kk << 2) | fq) ^ swr) << 4));
      #pragma unroll
      for (int j = 0; j < 4; ++j)
        #pragma unroll
        for (int jn = 0; jn < 2; ++jn)
          #pragma unroll
          for (int kk = 0; kk < 2; ++kk)
            acc[qm * 4 + j][qn * 2 + jn] = __builtin_amdgcn_mfma_f32_16x16x32_bf16(
                av[j][kk], bv[jn][kk], acc[qm * 4 + j][qn * 2 + jn], 0, 0, 0);
    }
  }

  // epilogue: C/D layout col=lane&15, row=(lane>>4)*4+r
  #pragma unroll
  for (int mi = 0; mi < 8; ++mi) {
    const int row = m0 + wm * 128 + mi * 16 + fq * 4;
    #pragma unroll
    for (int ni = 0; ni < 4; ++ni) {
      const int col = n0 + wn * 64 + ni * 16 + fr;
      const float bvv = bias[col];
      #pragma unroll
      for (int r = 0; r < 4; ++r)
        C[(size_t)(row + r) * N + col] = f2bf(acc[mi][ni][r] + bvv);
    }
  }
}

// ---------------- 128x128 m97-structure GEMM (small h projection) ----------------
__device__ __forceinline__ void stage_tile_128x64(const u16* __restrict__ src, int ld,
                                                  u16* lds, int tid) {
  int wid = tid >> 6;
  #pragma unroll
  for (int i = 0; i < 4; ++i) {
    int c = i * 256 + tid;
    const u16* g = src + (size_t)(c >> 3) * ld + ((c & 7) << 3);
    char* l = (char*)lds + ((i * 4 + wid) << 10);
    glds16(g, l);
  }
}

__global__ __launch_bounds__(256)
void gemm_bf16_nt_f32out(const u16* __restrict__ A, const u16* __restrict__ Bm,
                         const float* __restrict__ bias,
                         float* __restrict__ C, int K, int N) {
  __shared__ u16 sA[128 * 64];
  __shared__ u16 sB[128 * 64];

  int tid = threadIdx.x;
  const int m0 = blockIdx.x * 128, n0 = blockIdx.y * 128;
  const u16* Ap = A + (size_t)m0 * K;
  const u16* Bp = Bm + (size_t)n0 * K;

  int lane = tid & 63;
  int wid = tid >> 6;
  int wm = wid >> 1, wn = wid & 1;
  int fr = lane & 15;
  int fq = lane >> 4;

  f32x4 acc[4][4] = {};

  for (int k0 = 0; k0 < K; k0 += 64) {
    stage_tile_128x64(Ap + k0, K, sA, tid);
    stage_tile_128x64(Bp + k0, K, sB, tid);
    __syncthreads();
    #pragma unroll
    for (int kk = 0; kk < 2; ++kk) {
      bf16x8 af[4], bfrag[4];
      #pragma unroll
      for (int mi = 0; mi < 4; ++mi)
        af[mi] = *reinterpret_cast<const bf16x8*>(&sA[(wm * 64 + mi * 16 + fr) * 64 + kk * 32 + fq * 8]);
      #pragma unroll
      for (int nj = 0; nj < 4; ++nj)
        bfrag[nj] = *reinterpret_cast<const bf16x8*>(&sB[(wn * 64 + nj * 16 + fr) * 64 + kk * 32 + fq * 8]);
      #pragma unroll
      for (int mi = 0; mi < 4; ++mi)
        #pragma unroll
        for (int nj = 0; nj < 4; ++nj)
          acc[mi][nj] = __builtin_amdgcn_mfma_f32_16x16x32_bf16(af[mi], bfrag[nj], acc[mi][nj], 0, 0, 0);
    }
    __syncthreads();
  }

  #pragma unroll
  for (int nj = 0; nj < 4; ++nj) {
    int col = n0 + wn * 64 + nj * 16 + fr;
    float bv = bias[col];
    #pragma unroll
    for (int mi = 0; mi < 4; ++mi) {
      int rowb = m0 + wm * 64 + mi * 16 + fq * 4;
      #pragma unroll
      for (int r = 0; r < 4; ++r)
        C[(size_t)(rowb + r) * N + col] = acc[mi][nj][r] + bv;
    }
  }
}

// ---------------- group-wise online softmax + weighted sum ----------------
__global__ __launch_bounds__(256)
void seg_softmax(const u16* __restrict__ lg, const u16* __restrict__ vl,
                 const int* __restrict__ cnt, const int* __restrict__ offs,
                 const int* __restrict__ elist,
                 u16* __restrict__ y, int E, int D, int B, int G) {
  __shared__ int eids[256];
  int g = blockIdx.x / B;
  int b = blockIdx.x - g * B;
  int t = threadIdx.x;
  int n = cnt[g], start = offs[g];
  int d0 = t * 2;

  float m0 = -1e30f, m1 = -1e30f, s0 = 0.f, s1 = 0.f, a0 = 0.f, a1 = 0.f;
  for (int c0 = 0; c0 < n; c0 += 256) {
    int nc = n - c0; if (nc > 256) nc = 256;
    __syncthreads();
    if (t < nc) eids[t] = elist[start + c0 + t];
    __syncthreads();
    for (int i = 0; i < nc; ++i) {
      size_t base = ((size_t)b * E + eids[i]) * D + d0;
      uint32_t lu = *reinterpret_cast<const uint32_t*>(lg + base);
      uint32_t vu = *reinterpret_cast<const uint32_t*>(vl + base);
      float l0 = bf2f((u16)(lu & 0xffffu)), l1 = bf2f((u16)(lu >> 16));
      float v0 = bf2f((u16)(vu & 0xffffu)), v1 = bf2f((u16)(vu >> 16));
      float nm0 = fmaxf(m0, l0);
      float sc0 = __expf(m0 - nm0), w0 = __expf(l0 - nm0);
      s0 = s0 * sc0 + w0; a0 = a0 * sc0 + w0 * v0; m0 = nm0;
      float nm1 = fmaxf(m1, l1);
      float sc1 = __expf(m1 - nm1), w1 = __expf(l1 - nm1);
      s1 = s1 * sc1 + w1; a1 = a1 * sc1 + w1 * v1; m1 = nm1;
    }
  }
  float r0 = (n > 0) ? a0 / s0 : 0.f;
  float r1 = (n > 0) ? a1 / s1 : 0.f;
  size_t yoff = ((size_t)b * G + g) * D + d0;
  uint32_t o = (uint32_t)f2bf(r0) | ((uint32_t)f2bf(r1) << 16);
  *reinterpret_cast<uint32_t*>(y + yoff) = o;
}

// ---------------- gather rows back to edges (fp32 out) ----------------
__global__ void gather_k(const float* __restrict__ of, const int* __restrict__ ix,
                         float* __restrict__ out, int E, int D, int G) {
  int be = blockIdx.x;
  int b = be / E;
  int e = be - b * E;
  int gsel = ix[e];
  const float4* src = reinterpret_cast<const float4*>(of + ((size_t)b * G + gsel) * D);
  float4* dst = reinterpret_cast<float4*>(out + (size_t)be * D);
  for (int t = threadIdx.x; t < D / 4; t += blockDim.x)
    dst[t] = src[t];
}

extern "C" void kernel_launch(void* const* d_in, const int* in_sizes, int n_in,
                              void* d_out, int out_size, void* d_ws, size_t ws_size,
                              hipStream_t stream) {
  const float* x   = (const float*)d_in[0];
  const int*   ix  = (const int*)d_in[1];
  const float* Wf  = (const float*)d_in[2];
  const float* bfb = (const float*)d_in[3];
  const float* Wg  = (const float*)d_in[4];
  const float* bg  = (const float*)d_in[5];
  const float* Wh  = (const float*)d_in[6];
  const float* bh  = (const float*)d_in[7];

  const int E = in_sizes[1];
  const int D = in_sizes[3];
  const int B = in_sizes[0] / (E * D);
  const int G = NUM_GROUPS_C;
  const int M = B * E;

  char* ws = (char*)d_ws;
  size_t off = 0;
  auto alloc = [&](size_t bytes) -> char* {
    char* p = ws + off;
    off += (bytes + 255) & ~(size_t)255;
    return p;
  };
  u16* lgb = (u16*)alloc((size_t)M * D * 2);
  u16* vlb = (u16*)alloc((size_t)M * D * 2);
  u16* Wgb = (u16*)alloc((size_t)D * D * 2);
  u16* Wfb = (u16*)alloc((size_t)D * D * 2);
  u16* Whb = (u16*)alloc((size_t)D * D * 2);
  u16* yb  = (u16*)alloc((size_t)B * G * D * 2);
  float* ofb = (float*)alloc((size_t)B * G * D * 4);
  int* cnt    = (int*)alloc((size_t)G * 4);
  int* offs   = (int*)alloc((size_t)G * 4);
  int* cursor = (int*)alloc((size_t)G * 4);
  int* elist  = (int*)alloc((size_t)E * 4);

  // 1) weight casts (one launch); x is cast in-GEMM now
  dim3 gw(64, 3);
  cast_w3<<<gw, 256, 0, stream>>>(Wg, Wf, Wh, Wgb, Wfb, Whb, D * D / 4);

  // 2) bucket edges by group
  zero_i32<<<(G + 255) / 256, 256, 0, stream>>>(cnt, G);
  count_k<<<(E + 255) / 256, 256, 0, stream>>>(ix, cnt, E);
  scan_k<<<1, 256, 0, stream>>>(cnt, offs, cursor, G);
  scatter_k<<<(E + 255) / 256, 256, 0, stream>>>(ix, cursor, elist, E);

  // 3) fused f/g projections, fp32 A cast in-staging; (M/256)*4 blocks
  gemm256_fg<<<(M / 256) * 4, 512, 0, stream>>>(x, Wgb, Wfb, bg, bfb, lgb, vlb, D, D);

  // 4) group-wise softmax + weighted sum -> y (B,G,D) bf16
  seg_softmax<<<G * B, 256, 0, stream>>>(lgb, vlb, cnt, offs, elist, yb, E, D, B, G);

  // 5) h projection: (B*G, D) x (D, D) -> fp32
  dim3 gh((B * G) / 128, D / 128);
  gemm_bf16_nt_f32out<<<gh, 256, 0, stream>>>(yb, Whb, bh, ofb, D, D);

  // 6) gather to output (fp32)
  gather_k<<<B * E, 128, 0, stream>>>(ofb, ix, (float*)d_out, E, D, G);
}

// Round 10
// 221.984 us; speedup vs baseline: 1.0688x; 1.0688x over previous
//
#include <hip/hip_runtime.h>
#include <hip/hip_bf16.h>
#include <cstdint>
#include <cstddef>

typedef __bf16 bf16x8 __attribute__((ext_vector_type(8)));
typedef float f32x4 __attribute__((ext_vector_type(4)));
using u16 = unsigned short;

#define NUM_GROUPS_C 2048

__device__ __forceinline__ u16 f2bf(float f) {
  union { float f; uint32_t u; } c; c.f = f;
  uint32_t r = (c.u + 0x7fffu + ((c.u >> 16) & 1u)) >> 16;
  return (u16)r;
}
__device__ __forceinline__ float bf2f(u16 h) {
  union { uint32_t u; float f; } c; c.u = ((uint32_t)h) << 16; return c.f;
}

__device__ __forceinline__ void glds16(const u16* g, void* l) {
  __builtin_amdgcn_global_load_lds((const __attribute__((address_space(1))) void*)g,
                                   (__attribute__((address_space(3))) void*)l, 16, 0, 0);
}

// ---------------- cast fp32 -> bf16, vectorized ----------------
__global__ void cast_f32_bf16(const float* __restrict__ src, u16* __restrict__ dst, long n4) {
  long i = (long)blockIdx.x * blockDim.x + threadIdx.x;
  long stride = (long)gridDim.x * blockDim.x;
  for (; i < n4; i += stride) {
    float4 v = reinterpret_cast<const float4*>(src)[i];
    uint2 o;
    o.x = (uint32_t)f2bf(v.x) | ((uint32_t)f2bf(v.y) << 16);
    o.y = (uint32_t)f2bf(v.z) | ((uint32_t)f2bf(v.w) << 16);
    reinterpret_cast<uint2*>(dst)[i] = o;
  }
}

// ---------------- cast 3 weight matrices fp32 -> bf16 (one launch) ----------------
__global__ void cast_w3(const float* __restrict__ w0, const float* __restrict__ w1,
                        const float* __restrict__ w2,
                        u16* __restrict__ o0, u16* __restrict__ o1, u16* __restrict__ o2,
                        int n4) {
  const float* src = (blockIdx.y == 0) ? w0 : (blockIdx.y == 1) ? w1 : w2;
  u16* dst = (blockIdx.y == 0) ? o0 : (blockIdx.y == 1) ? o1 : o2;
  int i = blockIdx.x * blockDim.x + threadIdx.x;
  int stride = gridDim.x * blockDim.x;
  for (; i < n4; i += stride) {
    float4 v = reinterpret_cast<const float4*>(src)[i];
    uint2 o;
    o.x = (uint32_t)f2bf(v.x) | ((uint32_t)f2bf(v.y) << 16);
    o.y = (uint32_t)f2bf(v.z) | ((uint32_t)f2bf(v.w) << 16);
    reinterpret_cast<uint2*>(dst)[i] = o;
  }
}

// ---------------- bucket edges by group ----------------
__global__ void zero_i32(int* p, int n) {
  int i = blockIdx.x * blockDim.x + threadIdx.x;
  if (i < n) p[i] = 0;
}
__global__ void count_k(const int* __restrict__ ix, int* __restrict__ cnt, int E) {
  int e = blockIdx.x * blockDim.x + threadIdx.x;
  if (e < E) atomicAdd(&cnt[ix[e]], 1);
}
__global__ void scan_k(const int* __restrict__ cnt, int* __restrict__ offs,
                       int* __restrict__ cursor, int G) {
  __shared__ int part[256];
  int t = threadIdx.x;
  int gpt = G / 256;
  int base = t * gpt;
  int loc[8];
  int s = 0;
  for (int j = 0; j < gpt; ++j) { loc[j] = cnt[base + j]; s += loc[j]; }
  part[t] = s;
  __syncthreads();
  for (int off = 1; off < 256; off <<= 1) {
    int v = (t >= off) ? part[t - off] : 0;
    __syncthreads();
    part[t] += v;
    __syncthreads();
  }
  int run = part[t] - s;
  for (int j = 0; j < gpt; ++j) {
    offs[base + j] = run;
    cursor[base + j] = run;
    run += loc[j];
  }
}
__global__ void scatter_k(const int* __restrict__ ix, int* __restrict__ cursor,
                          int* __restrict__ elist, int E) {
  int e = blockIdx.x * blockDim.x + threadIdx.x;
  if (e < E) {
    int g = ix[e];
    int pos = atomicAdd(&cursor[g], 1);
    elist[pos] = e;
  }
}

// ============ f/g GEMM: 256x256 tile, BK=64, 8 waves, fine-grained 4-phase schedule ============
// C[m,n] = sum_k A[m,k]*B[n,k] + bias[n]; A (M,K) bf16 rm, B (N,K) bf16 rm.
// Fragment interleave: A-frag mi -> rows mi*32 + wm*16 + fr; B-frag nj -> rows nj*64 + wn*16 + fr.
//   => phase (quadrant) q reads EXACTLY half-tile q for every wave, enabling per-half staging lead.
// Per phase: { ds_read frags | stage 1 half-tile (2 glds) | vmcnt(4) | barrier | 16 MFMA | barrier }.
// Staging order per K-tile kt (for kt+1): [B0, A0, B1, A1].
// Queue proof (steady state, 4 ops left after each vmcnt(4)):
//   entering iter kt: [B1(kt), A1(kt)]; ph0 +B0(kt+1) -> retire B1(kt) (read ph2-next? no: read
//   THIS iter ph1 -- confirmed here, one phase ahead of its ph1 read). ph1 +A0(kt+1) -> retire
//   A1(kt) (read ph2). ph2 +B1(kt+1) -> retire B0(kt+1)... leaving [A0(kt+1), B1(kt+1)];
//   ph3 +A1(kt+1) -> retire A0(kt+1). Every half-tile confirmed >=1 phase+barrier before read.
// RACE FIX (R9 failure): prologue must drain its own first two half-tiles BEFORE iter-0 ph0's
//   ds_reads -> vmcnt(4) (retires B0(0), A0(0)) + s_barrier inserted after prologue.
// Tail: redundant restage of last K-tile keeps vmcnt semantics uniform (dead buffer; never read).
// LDS swizzle: LDS(row r, 16B-slot s) = global slot s^(r&7); staged via pre-swizzled source.
__global__ __launch_bounds__(512, 2)
void gemm256_fg8(const u16* __restrict__ A,
                 const u16* __restrict__ B0g, const u16* __restrict__ B1g,
                 const float* __restrict__ bias0, const float* __restrict__ bias1,
                 u16* __restrict__ C0, u16* __restrict__ C1,
                 int K, int N) {
  __shared__ u16 lds[65536];   // 2 bufs x (A 32KB + B 32KB) = 128 KiB

  const int tid  = threadIdx.x;
  const int lane = tid & 63;
  const int wid  = tid >> 6;
  const int wm   = wid >> 2;   // 0..1
  const int wn   = wid & 3;    // 0..3
  const int fr   = lane & 15;
  const int fq   = lane >> 4;
  const int swr  = fr & 7;     // read-side swizzle key (all frag rows ≡ fr mod 8)

  // bijective XCD swizzle; ns fastest within mt for A-panel L2 reuse
  const int nwg = gridDim.x, cpx = nwg >> 3, wg = blockIdx.x;
  const int swz = (wg & 7) * cpx + (wg >> 3);
  const int mt = swz >> 2, ns = swz & 3;
  const u16* Bm     = (ns < 2) ? B0g : B1g;
  const float* bias = (ns < 2) ? bias0 : bias1;
  u16* C            = (ns < 2) ? C0 : C1;
  const int n0 = (ns & 1) * 256, m0 = mt * 256;

  // staging geometry: per half-tile (128 rows x 64 cols), thread covers rows r8, r8+64,
  // 16B-slot tid&7; source column pre-swizzled (inverse of read-side XOR).
  const int r8   = tid >> 3;
  const int scol = ((tid & 7) ^ (r8 & 7)) << 3;
  const u16* Ab = A  + (size_t)m0 * K + scol;
  const u16* Bb = Bm + (size_t)n0 * K + scol;
  char* ldsb = (char*)lds;

  auto stage_ht = [&](int p, int isB, int h, int kt) {
    const u16* src = (isB ? Bb : Ab) + (size_t)(h * 128 + r8) * K + kt * 64;
    char* dst = ldsb + p * 65536 + isB * 32768 + h * 16384 + wid * 1024;
    glds16(src, dst);
    glds16(src + (size_t)64 * K, dst + 8192);
  };

#define RD_A(dst, mi_, kk_) \
  dst = *(const bf16x8*)(sA_ + (((mi_) * 32 + wm * 16 + fr) << 7) + (((((kk_) << 2) | fq) ^ swr) << 4))
#define RD_B(dst, nj_, kk_) \
  dst = *(const bf16x8*)(sB_ + (((nj_) * 64 + wn * 16 + fr) << 7) + (((((kk_) << 2) | fq) ^ swr) << 4))
#define MFMA_Q(accm, accn, af, bf_)                                                \
  __builtin_amdgcn_s_setprio(1);                                                  \
  _Pragma("unroll") for (int j = 0; j < 4; ++j)                                    \
  _Pragma("unroll") for (int jn = 0; jn < 2; ++jn)                                 \
  _Pragma("unroll") for (int kk = 0; kk < 2; ++kk)                                 \
    acc[(accm) + j][(accn) + jn] = __builtin_amdgcn_mfma_f32_16x16x32_bf16(        \
        af[j][kk], bf_[jn][kk], acc[(accm) + j][(accn) + jn], 0, 0, 0);            \
  __builtin_amdgcn_s_setprio(0);

  f32x4 acc[8][4] = {};
  const int NT = K >> 6;

  // prologue: K-tile 0 halves, order [B0, A0, B1, A1], into buf 0
  stage_ht(0, 1, 0, 0);
  stage_ht(0, 0, 0, 0);
  stage_ht(0, 1, 1, 0);
  stage_ht(0, 0, 1, 0);
  // RACE FIX: retire B0(0), A0(0) (phase 0's reads) before entering the loop.
  asm volatile("s_waitcnt vmcnt(4)" ::: "memory");
  __builtin_amdgcn_s_barrier();

  for (int kt = 0; kt < NT; ++kt) {
    const int cb = kt & 1, nb = cb ^ 1;
    const int ks = (kt + 1 < NT) ? kt + 1 : NT - 1;  // tail: redundant restage (dead buffer)
    const char* sA_ = ldsb + cb * 65536;
    const char* sB_ = sA_ + 32768;
    bf16x8 a0[4][2], a1[4][2], b0[2][2], b1[2][2];

    // ---- phase 0: read A-half0 + B-half0, MFMA quadrant (0,0) ----
    #pragma unroll
    for (int j = 0; j < 4; ++j) { RD_A(a0[j][0], j, 0); RD_A(a0[j][1], j, 1); }
    #pragma unroll
    for (int j = 0; j < 2; ++j) { RD_B(b0[j][0], j, 0); RD_B(b0[j][1], j, 1); }
    stage_ht(nb, 1, 0, ks);                              // B0(kt+1)
    asm volatile("s_waitcnt vmcnt(4)" ::: "memory");
    __builtin_amdgcn_s_barrier();
    MFMA_Q(0, 0, a0, b0)
    __builtin_amdgcn_s_barrier();

    // ---- phase 1: read B-half1, MFMA (0,1) ----
    #pragma unroll
    for (int j = 0; j < 2; ++j) { RD_B(b1[j][0], j + 2, 0); RD_B(b1[j][1], j + 2, 1); }
    stage_ht(nb, 0, 0, ks);                              // A0(kt+1)
    asm volatile("s_waitcnt vmcnt(4)" ::: "memory");
    __builtin_amdgcn_s_barrier();
    MFMA_Q(0, 2, a0, b1)
    __builtin_amdgcn_s_barrier();

    // ---- phase 2: read A-half1, MFMA (1,1) ----
    #pragma unroll
    for (int j = 0; j < 4; ++j) { RD_A(a1[j][0], j + 4, 0); RD_A(a1[j][1], j + 4, 1); }
    stage_ht(nb, 1, 1, ks);                              // B1(kt+1)
    asm volatile("s_waitcnt vmcnt(4)" ::: "memory");
    __builtin_amdgcn_s_barrier();
    MFMA_Q(4, 2, a1, b1)
    __builtin_amdgcn_s_barrier();

    // ---- phase 3: no LDS reads, MFMA (1,0) ----
    stage_ht(nb, 0, 1, ks);                              // A1(kt+1)
    asm volatile("s_waitcnt vmcnt(4)" ::: "memory");
    __builtin_amdgcn_s_barrier();
    MFMA_Q(4, 0, a1, b0)
    __builtin_amdgcn_s_barrier();
  }
  asm volatile("s_waitcnt vmcnt(0)" ::: "memory");       // retire tail restage DMA

  // epilogue: C/D layout col=lane&15, row=(lane>>4)*4+r; interleaved frag mapping
  #pragma unroll
  for (int mi = 0; mi < 8; ++mi) {
    const int row = m0 + mi * 32 + wm * 16 + fq * 4;
    #pragma unroll
    for (int ni = 0; ni < 4; ++ni) {
      const int col = n0 + ni * 64 + wn * 16 + fr;
      const float bvv = bias[col];
      #pragma unroll
      for (int r = 0; r < 4; ++r)
        C[(size_t)(row + r) * N + col] = f2bf(acc[mi][ni][r] + bvv);
    }
  }
#undef RD_A
#undef RD_B
#undef MFMA_Q
}

// ---------------- 128x128 m97-structure GEMM (small h projection) ----------------
__device__ __forceinline__ void stage_tile_128x64(const u16* __restrict__ src, int ld,
                                                  u16* lds, int tid) {
  int wid = tid >> 6;
  #pragma unroll
  for (int i = 0; i < 4; ++i) {
    int c = i * 256 + tid;
    const u16* g = src + (size_t)(c >> 3) * ld + ((c & 7) << 3);
    char* l = (char*)lds + ((i * 4 + wid) << 10);
    glds16(g, l);
  }
}

__global__ __launch_bounds__(256)
void gemm_bf16_nt_f32out(const u16* __restrict__ A, const u16* __restrict__ Bm,
                         const float* __restrict__ bias,
                         float* __restrict__ C, int K, int N) {
  __shared__ u16 sA[128 * 64];
  __shared__ u16 sB[128 * 64];

  int tid = threadIdx.x;
  const int m0 = blockIdx.x * 128, n0 = blockIdx.y * 128;
  const u16* Ap = A + (size_t)m0 * K;
  const u16* Bp = Bm + (size_t)n0 * K;

  int lane = tid & 63;
  int wid = tid >> 6;
  int wm = wid >> 1, wn = wid & 1;
  int fr = lane & 15;
  int fq = lane >> 4;

  f32x4 acc[4][4] = {};

  for (int k0 = 0; k0 < K; k0 += 64) {
    stage_tile_128x64(Ap + k0, K, sA, tid);
    stage_tile_128x64(Bp + k0, K, sB, tid);
    __syncthreads();
    #pragma unroll
    for (int kk = 0; kk < 2; ++kk) {
      bf16x8 af[4], bfrag[4];
      #pragma unroll
      for (int mi = 0; mi < 4; ++mi)
        af[mi] = *reinterpret_cast<const bf16x8*>(&sA[(wm * 64 + mi * 16 + fr) * 64 + kk * 32 + fq * 8]);
      #pragma unroll
      for (int nj = 0; nj < 4; ++nj)
        bfrag[nj] = *reinterpret_cast<const bf16x8*>(&sB[(wn * 64 + nj * 16 + fr) * 64 + kk * 32 + fq * 8]);
      #pragma unroll
      for (int mi = 0; mi < 4; ++mi)
        #pragma unroll
        for (int nj = 0; nj < 4; ++nj)
          acc[mi][nj] = __builtin_amdgcn_mfma_f32_16x16x32_bf16(af[mi], bfrag[nj], acc[mi][nj], 0, 0, 0);
    }
    __syncthreads();
  }

  #pragma unroll
  for (int nj = 0; nj < 4; ++nj) {
    int col = n0 + wn * 64 + nj * 16 + fr;
    float bv = bias[col];
    #pragma unroll
    for (int mi = 0; mi < 4; ++mi) {
      int rowb = m0 + wm * 64 + mi * 16 + fq * 4;
      #pragma unroll
      for (int r = 0; r < 4; ++r)
        C[(size_t)(rowb + r) * N + col] = acc[mi][nj][r] + bv;
    }
  }
}

// ---------------- group-wise online softmax + weighted sum ----------------
__global__ __launch_bounds__(256)
void seg_softmax(const u16* __restrict__ lg, const u16* __restrict__ vl,
                 const int* __restrict__ cnt, const int* __restrict__ offs,
                 const int* __restrict__ elist,
                 u16* __restrict__ y, int E, int D, int B, int G) {
  __shared__ int eids[256];
  int g = blockIdx.x / B;
  int b = blockIdx.x - g * B;
  int t = threadIdx.x;
  int n = cnt[g], start = offs[g];
  int d0 = t * 2;

  float m0 = -1e30f, m1 = -1e30f, s0 = 0.f, s1 = 0.f, a0 = 0.f, a1 = 0.f;
  for (int c0 = 0; c0 < n; c0 += 256) {
    int nc = n - c0; if (nc > 256) nc = 256;
    __syncthreads();
    if (t < nc) eids[t] = elist[start + c0 + t];
    __syncthreads();
    for (int i = 0; i < nc; ++i) {
      size_t base = ((size_t)b * E + eids[i]) * D + d0;
      uint32_t lu = *reinterpret_cast<const uint32_t*>(lg + base);
      uint32_t vu = *reinterpret_cast<const uint32_t*>(vl + base);
      float l0 = bf2f((u16)(lu & 0xffffu)), l1 = bf2f((u16)(lu >> 16));
      float v0 = bf2f((u16)(vu & 0xffffu)), v1 = bf2f((u16)(vu >> 16));
      float nm0 = fmaxf(m0, l0);
      float sc0 = __expf(m0 - nm0), w0 = __expf(l0 - nm0);
      s0 = s0 * sc0 + w0; a0 = a0 * sc0 + w0 * v0; m0 = nm0;
      float nm1 = fmaxf(m1, l1);
      float sc1 = __expf(m1 - nm1), w1 = __expf(l1 - nm1);
      s1 = s1 * sc1 + w1; a1 = a1 * sc1 + w1 * v1; m1 = nm1;
    }
  }
  float r0 = (n > 0) ? a0 / s0 : 0.f;
  float r1 = (n > 0) ? a1 / s1 : 0.f;
  size_t yoff = ((size_t)b * G + g) * D + d0;
  uint32_t o = (uint32_t)f2bf(r0) | ((uint32_t)f2bf(r1) << 16);
  *reinterpret_cast<uint32_t*>(y + yoff) = o;
}

// ---------------- gather rows back to edges (fp32 out) ----------------
__global__ void gather_k(const float* __restrict__ of, const int* __restrict__ ix,
                         float* __restrict__ out, int E, int D, int G) {
  int be = blockIdx.x;
  int b = be / E;
  int e = be - b * E;
  int gsel = ix[e];
  const float4* src = reinterpret_cast<const float4*>(of + ((size_t)b * G + gsel) * D);
  float4* dst = reinterpret_cast<float4*>(out + (size_t)be * D);
  for (int t = threadIdx.x; t < D / 4; t += blockDim.x)
    dst[t] = src[t];
}

extern "C" void kernel_launch(void* const* d_in, const int* in_sizes, int n_in,
                              void* d_out, int out_size, void* d_ws, size_t ws_size,
                              hipStream_t stream) {
  const float* x   = (const float*)d_in[0];
  const int*   ix  = (const int*)d_in[1];
  const float* Wf  = (const float*)d_in[2];
  const float* bfb = (const float*)d_in[3];
  const float* Wg  = (const float*)d_in[4];
  const float* bg  = (const float*)d_in[5];
  const float* Wh  = (const float*)d_in[6];
  const float* bh  = (const float*)d_in[7];

  const int E = in_sizes[1];
  const int D = in_sizes[3];
  const int B = in_sizes[0] / (E * D);
  const int G = NUM_GROUPS_C;
  const int M = B * E;
  const long xn = (long)M * D;

  char* ws = (char*)d_ws;
  size_t off = 0;
  auto alloc = [&](size_t bytes) -> char* {
    char* p = ws + off;
    off += (bytes + 255) & ~(size_t)255;
    return p;
  };
  u16* xb  = (u16*)alloc((size_t)M * D * 2);
  u16* lgb = (u16*)alloc((size_t)M * D * 2);
  u16* vlb = (u16*)alloc((size_t)M * D * 2);
  u16* Wgb = (u16*)alloc((size_t)D * D * 2);
  u16* Wfb = (u16*)alloc((size_t)D * D * 2);
  u16* Whb = (u16*)alloc((size_t)D * D * 2);
  u16* yb  = (u16*)alloc((size_t)B * G * D * 2);
  float* ofb = (float*)alloc((size_t)B * G * D * 4);
  int* cnt    = (int*)alloc((size_t)G * 4);
  int* offs   = (int*)alloc((size_t)G * 4);
  int* cursor = (int*)alloc((size_t)G * 4);
  int* elist  = (int*)alloc((size_t)E * 4);

  // 1) casts to bf16
  cast_f32_bf16<<<2048, 256, 0, stream>>>(x, xb, xn / 4);
  dim3 gw(64, 3);
  cast_w3<<<gw, 256, 0, stream>>>(Wg, Wf, Wh, Wgb, Wfb, Whb, D * D / 4);

  // 2) bucket edges by group
  zero_i32<<<(G + 255) / 256, 256, 0, stream>>>(cnt, G);
  count_k<<<(E + 255) / 256, 256, 0, stream>>>(ix, cnt, E);
  scan_k<<<1, 256, 0, stream>>>(cnt, offs, cursor, G);
  scatter_k<<<(E + 255) / 256, 256, 0, stream>>>(ix, cursor, elist, E);

  // 3) fused f/g projections, fine-grained 4-phase schedule; (M/256)*4 blocks
  gemm256_fg8<<<(M / 256) * 4, 512, 0, stream>>>(xb, Wgb, Wfb, bg, bfb, lgb, vlb, D, D);

  // 4) group-wise softmax + weighted sum -> y (B,G,D) bf16
  seg_softmax<<<G * B, 256, 0, stream>>>(lgb, vlb, cnt, offs, elist, yb, E, D, B, G);

  // 5) h projection: (B*G, D) x (D, D) -> fp32
  dim3 gh((B * G) / 128, D / 128);
  gemm_bf16_nt_f32out<<<gh, 256, 0, stream>>>(yb, Whb, bh, ofb, D, D);

  // 6) gather to output (fp32)
  gather_k<<<B * E, 128, 0, stream>>>(ofb, ix, (float*)d_out, E, D, G);
}